// Round 1
// baseline (291.002 us; speedup 1.0000x reference)
//
#include <hip/hip_runtime.h>
#include <hip/hip_bf16.h>

#define HIDDEN 64
#define EPS 1e-5f
#define NPB 64            // nodes per block (mm_relu and fused layer)
#define WST 72            // bf16 LDS row stride (shorts): 16B-aligned, breaks 128B aliasing

typedef __attribute__((ext_vector_type(8))) short bf16x8;   // MFMA A/B frag (4 VGPRs)
typedef __attribute__((ext_vector_type(4))) float f32x4;    // MFMA C/D frag

__device__ __forceinline__ unsigned short f2b(float x) {
    __hip_bfloat16 b = __float2bfloat16(x);
    return *(unsigned short*)&b;
}
__device__ __forceinline__ float b2f(unsigned short u) {
    unsigned int ui = (unsigned int)u << 16;
    return *(float*)&ui;
}
__device__ __forceinline__ float b2f_lo(unsigned int u) { unsigned int ui = u << 16; return *(float*)&ui; }
__device__ __forceinline__ float b2f_hi(unsigned int u) { unsigned int ui = u & 0xffff0000u; return *(float*)&ui; }
__device__ __forceinline__ unsigned int pk2(float a, float b) {
    return (unsigned int)f2b(a) | ((unsigned int)f2b(b) << 16);
}

// ---------------- CSR build ----------------

__global__ __launch_bounds__(256) void hist_rank_kernel(const int* __restrict__ row,
                                                        int* __restrict__ cnt,
                                                        int* __restrict__ erank, int e) {
    int stride = gridDim.x * blockDim.x;
    for (int i = blockIdx.x * blockDim.x + threadIdx.x; i < e; i += stride) {
        int r = row[i];
        erank[i] = atomicAdd(&cnt[r], 1);
    }
}

__global__ __launch_bounds__(256) void block_sum_kernel(const int* __restrict__ cnt,
                                                        int* __restrict__ bsum, int n) {
    __shared__ int wsum[4];
    int tid = threadIdx.x;
    int i = blockIdx.x * 256 + tid;
    int v = (i < n) ? cnt[i] : 0;
#pragma unroll
    for (int off = 32; off > 0; off >>= 1) v += __shfl_xor(v, off, 64);
    if ((tid & 63) == 0) wsum[tid >> 6] = v;
    __syncthreads();
    if (tid == 0) bsum[blockIdx.x] = wsum[0] + wsum[1] + wsum[2] + wsum[3];
}

// scan_final with inline block-prefix: block b sums bsum[0..b) itself
__global__ __launch_bounds__(256) void scan_final_kernel(const int* __restrict__ cnt,
                                                         const int* __restrict__ bsum,
                                                         int* __restrict__ row_ptr,
                                                         int n, int nb) {
    __shared__ int wred[4];
    __shared__ int wsum[4];
    __shared__ int wexcl[4];
    __shared__ int s_prev;
    __shared__ int s_tot;
    int b = blockIdx.x;
    int tid = threadIdx.x;
    int lane = tid & 63;
    int w = tid >> 6;
    int acc = 0;
    for (int j = tid; j < b; j += 256) acc += bsum[j];
#pragma unroll
    for (int off = 32; off > 0; off >>= 1) acc += __shfl_xor(acc, off, 64);
    if (lane == 0) wred[w] = acc;
    int i = b * 256 + tid;
    int v = (i < n) ? cnt[i] : 0;
    int sc = v;
#pragma unroll
    for (int off = 1; off < 64; off <<= 1) {
        int t = __shfl_up(sc, off, 64);
        if (lane >= off) sc += t;
    }
    if (lane == 63) wsum[w] = sc;
    __syncthreads();
    if (tid == 0) {
        s_prev = wred[0] + wred[1] + wred[2] + wred[3];
        int a = 0;
#pragma unroll
        for (int j = 0; j < 4; j++) { wexcl[j] = a; a += wsum[j]; }
        s_tot = a;
    }
    __syncthreads();
    if (i < n) row_ptr[i] = s_prev + wexcl[w] + (sc - v);
    if (b == nb - 1 && tid == 0) row_ptr[n] = s_prev + s_tot;
}

__global__ __launch_bounds__(256) void fill_kernel(const int* __restrict__ row,
                                                   const int* __restrict__ col,
                                                   const int* __restrict__ row_ptr,
                                                   const int* __restrict__ erank,
                                                   int* __restrict__ ecol, int e, int n) {
    int cls = blockIdx.x & 7;
    int sub = blockIdx.x >> 3;
    int nsub = gridDim.x >> 3;
    int lo = (int)(((long long)n * cls) >> 3);
    int hi = (int)(((long long)n * (cls + 1)) >> 3);
    for (int i = sub * 256 + threadIdx.x; i < e; i += nsub * 256) {
        int r = row[i];
        if (r >= lo && r < hi) {
            int pos = row_ptr[r] + erank[i];
            ecol[pos] = col[i];
        }
    }
}

// pre-convert all 2L weight matrices to bf16, [o][k] row-major (= MFMA B layout)
__global__ __launch_bounds__(256) void wconv_kernel(const float* __restrict__ cw,
                                                    const float* __restrict__ hw,
                                                    unsigned short* __restrict__ wbt, int L) {
    int idx = blockIdx.x * blockDim.x + threadIdx.x;
    int total = 2 * L * 4096;
    if (idx >= total) return;
    int mat = idx >> 12;
    int rem = idx & 4095;
    const float* src = (mat < L) ? (cw + (size_t)mat * 4096) : (hw + (size_t)(mat - L) * 4096);
    wbt[idx] = f2b(src[rem]);
}

// ---------------- MFMA helpers ----------------
// A tile: s_a[node][k] bf16 stride WST; wave computes nodes wbase..wbase+15.
// B tile: s_b[o][k] bf16 stride WST. D layout: col=l16, row=quad*4+reg.

__device__ __forceinline__ void mfma_tile(const unsigned short* s_a,
                                          const unsigned short* s_b,
                                          int l16, int quad, int wbase, f32x4 acc[4]) {
    const unsigned short* ap = &s_a[(size_t)(wbase + l16) * WST + quad * 8];
    const unsigned short* bp = &s_b[(size_t)l16 * WST + quad * 8];
#pragma unroll
    for (int kt = 0; kt < 2; kt++) {
        bf16x8 a = *(const bf16x8*)(ap + kt * 32);
#pragma unroll
        for (int nt = 0; nt < 4; nt++) {
            bf16x8 b = *(const bf16x8*)(bp + (size_t)nt * 16 * WST + kt * 32);
            acc[nt] = __builtin_amdgcn_mfma_f32_16x16x32_bf16(a, b, acc[nt], 0, 0, 0);
        }
    }
}

// stage a pre-converted bf16 weight matrix (plain copy into padded LDS rows)
__device__ __forceinline__ void stage_wb(const unsigned short* __restrict__ wsrc,
                                         unsigned short* s_wb, int tid) {
    for (int i = tid; i < 512; i += 256) {
        int r = i >> 3, seg = i & 7;
        *(uint4*)(&s_wb[r * WST + seg * 8]) = ((const uint4*)(wsrc + r * 64))[seg];
    }
}

// accumulate 8 bf16 values (one uint4) into p[0..7], masked by ok
__device__ __forceinline__ void acc8(float* p, uint4 u, bool ok) {
    p[0] += ok ? b2f_lo(u.x) : 0.f;
    p[1] += ok ? b2f_hi(u.x) : 0.f;
    p[2] += ok ? b2f_lo(u.y) : 0.f;
    p[3] += ok ? b2f_hi(u.y) : 0.f;
    p[4] += ok ? b2f_lo(u.z) : 0.f;
    p[5] += ok ? b2f_hi(u.z) : 0.f;
    p[6] += ok ? b2f_lo(u.w) : 0.f;
    p[7] += ok ? b2f_hi(u.w) : 0.f;
}

// ---------------- initial conv matmul: m = bf16(relu(x @ cw0^T)) ----------------

__global__ __launch_bounds__(256) void mm_relu_kernel(const float* __restrict__ h,
                                                      const unsigned short* __restrict__ wb,
                                                      __hip_bfloat16* __restrict__ m, int n) {
    __shared__ unsigned short s_hb[NPB * WST];
    __shared__ unsigned short s_wb[64 * WST];
    int tid = threadIdx.x;
    int base = blockIdx.x * NPB;
    stage_wb(wb, s_wb, tid);
    for (int i = tid; i < 512; i += 256) {
        int r = i >> 3, seg = i & 7;
        if (base + r < n) {
            const float4* hp = (const float4*)(h + (size_t)(base + r) * HIDDEN + seg * 8);
            float4 ha = hp[0], hb = hp[1];
            uint4 p;
            p.x = pk2(ha.x, ha.y);
            p.y = pk2(ha.z, ha.w);
            p.z = pk2(hb.x, hb.y);
            p.w = pk2(hb.z, hb.w);
            *(uint4*)(&s_hb[r * WST + seg * 8]) = p;
        } else {
            *(uint4*)(&s_hb[r * WST + seg * 8]) = make_uint4(0u, 0u, 0u, 0u);
        }
    }
    __syncthreads();
    int lane = tid & 63, wave = tid >> 6;
    int quad = lane >> 4, l16 = lane & 15;
    int wbase = wave * 16;
    f32x4 acc[4];
    acc[0] = (f32x4){0.f,0.f,0.f,0.f}; acc[1] = (f32x4){0.f,0.f,0.f,0.f};
    acc[2] = (f32x4){0.f,0.f,0.f,0.f}; acc[3] = (f32x4){0.f,0.f,0.f,0.f};
    mfma_tile(s_hb, s_wb, l16, quad, wbase, acc);
    unsigned short* mo = (unsigned short*)m;
#pragma unroll
    for (int r = 0; r < 4; r++) {
        int node = base + wbase + quad * 4 + r;
        if (node < n) {
#pragma unroll
            for (int nt = 0; nt < 4; nt++)
                mo[(size_t)node * HIDDEN + nt * 16 + l16] = f2b(fmaxf(acc[nt][r], 0.f));
        }
    }
}

// ---------------- fused layer kernel ----------------
// Block = 256 thr = 4 waves, 64 nodes. Wave w owns nodes wbase..wbase+15 —
// exactly its MFMA A-tile rows, so phase A -> B needs NO barrier for A data.
// LDS = s_hb (A tile) + s_wb (hidden weights) = 18432 B -> 8 blocks/CU
// (was 27648/5 blocks with a second weight buffer; phase-C conv weights are
// L2-hot 8KB read by every block, so they're loaded global->register instead).
// Phase A: 4 lanes per node, all 16 nodes of a wave gathered in ONE round
// (halves the serialized round count vs the old 2x8 scheme); ecol for the
// next iteration is prefetched so its latency hides under the gathers;
// accumulators p[16] are initialized directly from h (residual).
// Phase B: hidden MFMA + residual (own LDS rows) + rmsnorm -> h_new.
// Phase C: MFMA with next conv weights (global->reg B-frags) -> relu -> m_out.

__global__ __launch_bounds__(256) void fused_layer_kernel(
        const float* hf, const __hip_bfloat16* hb_in,
        const __hip_bfloat16* __restrict__ m_in,
        const unsigned short* __restrict__ hwb,
        const unsigned short* cwb_next,
        const int* __restrict__ row_ptr, const int* __restrict__ ecol,
        const float* __restrict__ cnw, const float* __restrict__ hnw,
        float* out_f32, __hip_bfloat16* hb_new, __hip_bfloat16* m_out, int n) {
    __shared__ unsigned short s_hb[NPB * WST];
    __shared__ unsigned short s_wb[64 * WST];
    int tid = threadIdx.x;
    int base = blockIdx.x * NPB;
    int lane = tid & 63, wave = tid >> 6;

    // stage hidden weights early (completes during phase A)
    stage_wb(hwb, s_wb, tid);

    // ---- Phase A: 16 nodes per wave, 4 lanes (16 cols) per node ----
    int g = lane >> 2;          // node index within wave tile (0..15)
    int sl = lane & 3;          // 16-column slice (cols 16*sl .. 16*sl+15)
    int gb = lane & ~3;         // first lane of this 4-lane group
    int nl = wave * 16 + g;
    int node = base + nl;

    const float4* cp = (const float4*)(cnw + 16 * sl);
    float4 c0 = cp[0], c1 = cp[1], c2 = cp[2], c3 = cp[3];
    const unsigned short* mi = (const unsigned short*)m_in;

    uint4 q0 = make_uint4(0u, 0u, 0u, 0u);
    uint4 q1 = make_uint4(0u, 0u, 0u, 0u);
    if (node < n) {
        float p[16];
        if (hf) {
            const float4* hp = (const float4*)(hf + (size_t)node * HIDDEN + 16 * sl);
            float4 v0 = hp[0], v1 = hp[1], v2 = hp[2], v3 = hp[3];
            p[0]=v0.x;  p[1]=v0.y;  p[2]=v0.z;  p[3]=v0.w;
            p[4]=v1.x;  p[5]=v1.y;  p[6]=v1.z;  p[7]=v1.w;
            p[8]=v2.x;  p[9]=v2.y;  p[10]=v2.z; p[11]=v2.w;
            p[12]=v3.x; p[13]=v3.y; p[14]=v3.z; p[15]=v3.w;
        } else {
            const uint4* hp = (const uint4*)((const unsigned short*)hb_in + (size_t)node * HIDDEN + 16 * sl);
            uint4 u0 = hp[0], u1 = hp[1];
            p[0]=b2f_lo(u0.x);  p[1]=b2f_hi(u0.x);
            p[2]=b2f_lo(u0.y);  p[3]=b2f_hi(u0.y);
            p[4]=b2f_lo(u0.z);  p[5]=b2f_hi(u0.z);
            p[6]=b2f_lo(u0.w);  p[7]=b2f_hi(u0.w);
            p[8]=b2f_lo(u1.x);  p[9]=b2f_hi(u1.x);
            p[10]=b2f_lo(u1.y); p[11]=b2f_hi(u1.y);
            p[12]=b2f_lo(u1.z); p[13]=b2f_hi(u1.z);
            p[14]=b2f_lo(u1.w); p[15]=b2f_hi(u1.w);
        }
        int beg = row_ptr[node];
        int end = row_ptr[node + 1];
        int myc = 0;
        if (beg < end) {
            int idx = beg + sl;
            myc = ecol[idx < end ? idx : end - 1];
        }
        for (int b0 = beg; b0 < end; b0 += 4) {
            int nxt = b0 + 4;
            int nmyc = 0;
            if (nxt < end) {                       // prefetch next iteration's ecol
                int idx = nxt + sl;
                nmyc = ecol[idx < end ? idx : end - 1];
            }
            int cnt = end - b0;
            if (cnt > 4) cnt = 4;
            int cj[4];
#pragma unroll
            for (int j = 0; j < 4; j++) cj[j] = __shfl(myc, gb + j, 64);
            uint4 ua[4], ub[4];
#pragma unroll
            for (int j = 0; j < 4; j++) {
                const uint4* mp = (const uint4*)(mi + (size_t)cj[j] * HIDDEN + 16 * sl);
                ua[j] = mp[0];
                ub[j] = mp[1];
            }
#pragma unroll
            for (int j = 0; j < 4; j++) {
                bool ok = j < cnt;
                acc8(p, ua[j], ok);
                acc8(p + 8, ub[j], ok);
            }
            myc = nmyc;
        }
        float ss = 0.f;
#pragma unroll
        for (int k = 0; k < 16; k++) ss += p[k] * p[k];
        ss += __shfl_xor(ss, 1, 64);
        ss += __shfl_xor(ss, 2, 64);
        float inv = rsqrtf(ss * (1.0f / 64.0f) + EPS);
        q0.x = pk2(p[0]*inv*c0.x,  p[1]*inv*c0.y);
        q0.y = pk2(p[2]*inv*c0.z,  p[3]*inv*c0.w);
        q0.z = pk2(p[4]*inv*c1.x,  p[5]*inv*c1.y);
        q0.w = pk2(p[6]*inv*c1.z,  p[7]*inv*c1.w);
        q1.x = pk2(p[8]*inv*c2.x,  p[9]*inv*c2.y);
        q1.y = pk2(p[10]*inv*c2.z, p[11]*inv*c2.w);
        q1.z = pk2(p[12]*inv*c3.x, p[13]*inv*c3.y);
        q1.w = pk2(p[14]*inv*c3.z, p[15]*inv*c3.w);
    }
    *(uint4*)(&s_hb[(size_t)nl * WST + 16 * sl]) = q0;
    *(uint4*)(&s_hb[(size_t)nl * WST + 16 * sl + 8]) = q1;
    __syncthreads();   // weight-tile visibility (A-tile rows are wave-private)

    // ---- Phase B ----
    int quad = lane >> 4, l16 = lane & 15;
    int wbase = wave * 16;
    f32x4 acc[4];
    acc[0] = (f32x4){0.f,0.f,0.f,0.f}; acc[1] = (f32x4){0.f,0.f,0.f,0.f};
    acc[2] = (f32x4){0.f,0.f,0.f,0.f}; acc[3] = (f32x4){0.f,0.f,0.f,0.f};
    mfma_tile(s_hb, s_wb, l16, quad, wbase, acc);

    float hv[4][4];
    float ssq[4] = {0.f, 0.f, 0.f, 0.f};
#pragma unroll
    for (int r = 0; r < 4; r++) {
        int nr = wbase + quad * 4 + r;
#pragma unroll
        for (int nt = 0; nt < 4; nt++) {
            float hres = b2f(s_hb[(size_t)nr * WST + nt * 16 + l16]);
            float v = hres + fmaxf(acc[nt][r], 0.f);
            hv[r][nt] = v;
            ssq[r] += v * v;
        }
    }
#pragma unroll
    for (int mk = 1; mk <= 8; mk <<= 1) {
#pragma unroll
        for (int r = 0; r < 4; r++) ssq[r] += __shfl_xor(ssq[r], mk, 64);
    }
    float nwv[4];
#pragma unroll
    for (int nt = 0; nt < 4; nt++) nwv[nt] = hnw[nt * 16 + l16];
#pragma unroll
    for (int r = 0; r < 4; r++) {
        float inv = rsqrtf(ssq[r] * (1.0f / 64.0f) + EPS);
#pragma unroll
        for (int nt = 0; nt < 4; nt++) hv[r][nt] *= inv * nwv[nt];
    }
    if (out_f32) {
#pragma unroll
        for (int r = 0; r < 4; r++) {
            int nd = base + wbase + quad * 4 + r;
            if (nd < n) {
#pragma unroll
                for (int nt = 0; nt < 4; nt++)
                    out_f32[(size_t)nd * HIDDEN + nt * 16 + l16] = hv[r][nt];
            }
        }
    }
    if (hb_new) {
        unsigned short* ho = (unsigned short*)hb_new;
#pragma unroll
        for (int r = 0; r < 4; r++) {
            int nd = base + wbase + quad * 4 + r;
            if (nd < n) {
#pragma unroll
                for (int nt = 0; nt < 4; nt++)
                    ho[(size_t)nd * HIDDEN + nt * 16 + l16] = f2b(hv[r][nt]);
            }
        }
    }

    if (!m_out) return;

    // ---- Phase C weights: global -> register B-fragments (L2-hot 8KB) ----
    // Issued before the D->A LDS writes so the global latency hides under them.
    bf16x8 wf[8];
    {
        const unsigned short* wp = cwb_next + (size_t)l16 * 64 + quad * 8;
#pragma unroll
        for (int nt = 0; nt < 4; nt++) {
#pragma unroll
            for (int kt = 0; kt < 2; kt++)
                wf[nt * 2 + kt] = *(const bf16x8*)(wp + (size_t)nt * 16 * 64 + kt * 32);
        }
    }

    // ---- D -> A layout (own rows only; intra-wave, no barrier) ----
#pragma unroll
    for (int r = 0; r < 4; r++) {
        int nr = wbase + quad * 4 + r;
#pragma unroll
        for (int nt = 0; nt < 4; nt++)
            s_hb[(size_t)nr * WST + nt * 16 + l16] = f2b(hv[r][nt]);
    }

    // ---- Phase C ----
    f32x4 acc2[4];
    acc2[0] = (f32x4){0.f,0.f,0.f,0.f}; acc2[1] = (f32x4){0.f,0.f,0.f,0.f};
    acc2[2] = (f32x4){0.f,0.f,0.f,0.f}; acc2[3] = (f32x4){0.f,0.f,0.f,0.f};
    {
        const unsigned short* ap = &s_hb[(size_t)(wbase + l16) * WST + quad * 8];
#pragma unroll
        for (int kt = 0; kt < 2; kt++) {
            bf16x8 a = *(const bf16x8*)(ap + kt * 32);
#pragma unroll
            for (int nt = 0; nt < 4; nt++)
                acc2[nt] = __builtin_amdgcn_mfma_f32_16x16x32_bf16(a, wf[nt * 2 + kt], acc2[nt], 0, 0, 0);
        }
    }
    unsigned short* mo = (unsigned short*)m_out;
#pragma unroll
    for (int r = 0; r < 4; r++) {
        int nd = base + wbase + quad * 4 + r;
        if (nd < n) {
#pragma unroll
            for (int nt = 0; nt < 4; nt++)
                mo[(size_t)nd * HIDDEN + nt * 16 + l16] = f2b(fmaxf(acc2[nt][r], 0.f));
        }
    }
}

// ---------------- launch ----------------

static inline size_t align_up(size_t x, size_t a) { return (x + a - 1) & ~(a - 1); }

extern "C" void kernel_launch(void* const* d_in, const int* in_sizes, int n_in,
                              void* d_out, int out_size, void* d_ws, size_t ws_size,
                              hipStream_t stream) {
    const float* x       = (const float*)d_in[0];
    const float* conv_w  = (const float*)d_in[1];
    const float* conv_nw = (const float*)d_in[2];
    const float* hid_w   = (const float*)d_in[3];
    const float* hid_nw  = (const float*)d_in[4];
    const int*   row     = (const int*)d_in[5];
    const int*   col     = (const int*)d_in[6];
    float* out = (float*)d_out;

    const int n = in_sizes[0] / HIDDEN;   // 100000
    const int e = in_sizes[5];            // 800000
    const int L = in_sizes[1] / 4096;     // 4

    // workspace layout
    size_t off = 0;
    char* ws = (char*)d_ws;
    __hip_bfloat16* mA = (__hip_bfloat16*)(ws + off);  off = align_up(off + (size_t)n * HIDDEN * 2, 16);
    __hip_bfloat16* mB = (__hip_bfloat16*)(ws + off);  off = align_up(off + (size_t)n * HIDDEN * 2, 16);
    __hip_bfloat16* hb1 = (__hip_bfloat16*)(ws + off); off = align_up(off + (size_t)n * HIDDEN * 2, 16);
    __hip_bfloat16* hb2 = (__hip_bfloat16*)(ws + off); off = align_up(off + (size_t)n * HIDDEN * 2, 16);
    unsigned short* wbt = (unsigned short*)(ws + off); off = align_up(off + (size_t)2 * L * 4096 * 2, 16);
    int* row_ptr = (int*)(ws + off);           off = align_up(off + (size_t)(n + 1) * 4, 16);
    int* cnt = (int*)(ws + off);               off = align_up(off + (size_t)n * 4, 16);
    int* bsum = (int*)(ws + off);              off = align_up(off + (size_t)1024 * 4, 16);
    int* erank = (int*)(ws + off);             off = align_up(off + (size_t)e * 4, 16);
    int* ecol = (int*)(ws + off);              off = align_up(off + (size_t)e * 4, 16);

    const int nb = (n + 255) / 256;

    // CSR build (once per launch; edges constant across layers)
    hipMemsetAsync(cnt, 0, (size_t)n * 4, stream);
    hist_rank_kernel<<<1024, 256, 0, stream>>>(row, cnt, erank, e);
    block_sum_kernel<<<nb, 256, 0, stream>>>(cnt, bsum, n);
    scan_final_kernel<<<nb, 256, 0, stream>>>(cnt, bsum, row_ptr, n, nb);
    fill_kernel<<<1024, 256, 0, stream>>>(row, col, row_ptr, erank, ecol, e, n);

    // weights -> bf16 once
    wconv_kernel<<<(2 * L * 4096 + 255) / 256, 256, 0, stream>>>(conv_w, hid_w, wbt, L);

    const int blocks = (n + NPB - 1) / NPB;

    // initial conv matmul for layer 0
    mm_relu_kernel<<<blocks, 256, 0, stream>>>(x, wbt, mA, n);

    const __hip_bfloat16* mi = mA;
    __hip_bfloat16* mo = mB;
    __hip_bfloat16* hin = nullptr;   // layer 0 uses x (f32)
    __hip_bfloat16* hout = hb1;
    for (int l = 0; l < L; l++) {
        bool last = (l == L - 1);
        fused_layer_kernel<<<blocks, 256, 0, stream>>>(
            (l == 0) ? x : nullptr, hin, mi,
            wbt + (size_t)(L + l) * 4096,
            last ? nullptr : (wbt + (size_t)(l + 1) * 4096),
            row_ptr, ecol,
            conv_nw + (size_t)l * HIDDEN, hid_nw + (size_t)l * HIDDEN,
            last ? out : nullptr,
            last ? nullptr : hout,
            last ? nullptr : mo, n);
        __hip_bfloat16* tmp = (__hip_bfloat16*)mi; mi = mo; mo = tmp;
        hin = hout;
        hout = (hout == hb1) ? hb2 : hb1;
    }
}